// Round 1
// baseline (1450.910 us; speedup 1.0000x reference)
//
#include <hip/hip_runtime.h>

#define BATCH 4096
#define SEQ   2048
#define EMB   10
#define HID   50
#define VOCAB 14
#define G4    200      // 4*HID gate rows
#define NT    13       // 13 N-tiles of 16 cover 208 >= 200 interleaved gate rows
#define HSTR  72       // bf16 stride of one batch row in h buffer (64 used + 8 pad)
#define TSTR  20       // int stride of token chunk row (16 used + 4 pad, keeps 16B align)

using bf16x8 = __attribute__((ext_vector_type(8))) short;
using f32x4  = __attribute__((ext_vector_type(4))) float;

__device__ __forceinline__ short f2bf(float f) {
  unsigned u = __builtin_bit_cast(unsigned, f);
  u = (u + 0x7FFFu + ((u >> 16) & 1u)) >> 16;   // round-to-nearest-even
  return (short)u;
}
__device__ __forceinline__ float fsigm(float x) {
  return __builtin_amdgcn_rcpf(1.0f + __builtin_amdgcn_exp2f(x * -1.44269504f));
}
__device__ __forceinline__ float ftanh(float x) {
  return 2.0f * __builtin_amdgcn_rcpf(1.0f + __builtin_amdgcn_exp2f(x * -2.88539008f)) - 1.0f;
}

// ---------------------------------------------------------------------------
// Setup: pack A-operand fragments (bf16) for mfma_f32_16x16x32_bf16.
// A[m][k] per tile t: m = lane&15 -> interleaved gate row n' = 16t+m
//                     k = kf*32 + (lane>>4)*8 + j
//   n' = 4*j_h + g  maps to original row r = 50*g + j_h  (i,f,g,o interleave)
//   k <  50 : W_hh[r][k]
//   k >= 50 : gxi[v = k-50][n'] = b_ih[r]+b_hh[r]+sum_e emb[v][e]*W_ih[r][e]
// (one-hot token rows fold embedding+input-proj+biases into the same MFMA)
// ---------------------------------------------------------------------------
__global__ void prep_kernel(const float* __restrict__ emb,  const float* __restrict__ W_ih,
                            const float* __restrict__ W_hh, const float* __restrict__ b_ih,
                            const float* __restrict__ b_hh, short* __restrict__ Apack) {
  int idx = blockIdx.x * 256 + threadIdx.x;       // total NT*2*64*8 = 13312
  if (idx >= NT * 2 * 64 * 8) return;
  int j    = idx & 7;
  int lane = (idx >> 3) & 63;
  int kf   = (idx >> 9) & 1;
  int t    = idx >> 10;
  int m    = lane & 15;
  int n    = t * 16 + m;                           // interleaved gate row
  int k    = kf * 32 + (lane >> 4) * 8 + j;
  float v = 0.0f;
  if (n < G4) {
    int jh = n >> 2, g = n & 3;
    int r  = g * HID + jh;                         // original gate row (i,f,g,o blocks)
    if (k < HID) {
      v = W_hh[r * HID + k];
    } else {
      int vo = k - HID;                            // vocab id 0..13
      float s = b_ih[r] + b_hh[r];
      for (int e = 0; e < EMB; ++e) s += emb[vo * EMB + e] * W_ih[r * EMB + e];
      v = s;
    }
  }
  Apack[idx] = f2bf(v);
}

// ---------------------------------------------------------------------------
// Main: 256 wgs x 512 threads (8 waves). One wg owns 16 batch rows for the
// whole sequence. Per step: B-frag = h(bf16)+onehot from LDS, 2 MFMAs/tile,
// lane-local i/f/g/o -> c,h update, write h back to ping-pong buffer.
// Waves 0-4: tiles {2w,2w+1}; wave5: 10; wave6: 11; wave7: 12 + token utility.
// ---------------------------------------------------------------------------
__global__ __launch_bounds__(512, 2) void lstm_kernel(
    const int* __restrict__ tokens, const short* __restrict__ Apack,
    const float* __restrict__ W1, const float* __restrict__ b1,
    const float* __restrict__ W2, const float* __restrict__ b2,
    float* __restrict__ out) {
  __shared__ __align__(16) short hbuf[2][16 * HSTR];   // [buf][b][k] bf16: k<50 h, 50..63 onehot
  __shared__ __align__(16) int   tokc[2][16 * TSTR];   // token chunks (16 steps)
  __shared__ float hfin[16 * 52];                      // final h (f32)
  __shared__ float mlp_hid[16 * 52];

  const int tid  = threadIdx.x;
  const int lane = tid & 63;
  const int wv   = tid >> 6;
  const int b0   = blockIdx.x * 16;
  const int bB   = lane & 15;          // batch col (B-frag & C col)
  const int jj   = lane >> 4;          // quad -> hidden offset within tile
  const int q8   = jj * 8;             // k octet base

  int nt_own, t0;
  if (wv < 5) { nt_own = 2; t0 = wv * 2; }
  else        { nt_own = 1; t0 = wv + 5; }             // 10, 11, 12

  // persistent A fragments (weights + gxi), loaded once
  bf16x8 Af[2][2];
  for (int i = 0; i < nt_own; ++i)
    for (int kf = 0; kf < 2; ++kf)
      Af[i][kf] = *(const bf16x8*)(Apack + (((t0 + i) * 2 + kf) * 64 + lane) * 8);

  // ---- init: zero h rows of buf0, load token chunk 0, write onehot for t=0
  for (int i = tid; i < 16 * HSTR; i += 512) hbuf[0][i] = 0;
  __syncthreads();
  int4 tokreg = {0, 0, 0, 0};
  if (wv == 7) {
    int bb = lane >> 2, d4 = (lane & 3) * 4;
    tokreg = *(const int4*)&tokens[(b0 + bb) * SEQ + d4];
    *(int4*)&tokc[0][bb * TSTR + d4] = tokreg;
    for (int i = lane; i < 256; i += 64) {
      int b = i >> 4, v = i & 15;
      if (v < VOCAB)
        hbuf[0][b * HSTR + HID + v] = (tokc[0][b * TSTR + 0] == v) ? (short)0x3F80 : (short)0;
    }
  }

  float c0 = 0.f, c1 = 0.f, h0 = 0.f, h1 = 0.f;

  for (int t = 0; t < SEQ; ++t) {
    const int p = t & 1, pn = p ^ 1;
    __syncthreads();   // hbuf[p] and current token chunk are ready

    // B fragment: B[k][n=bB], k = q8..q8+7 (+32 for kf=1)
    bf16x8 Bf0 = *(const bf16x8*)&hbuf[p][bB * HSTR + q8];
    bf16x8 Bf1 = *(const bf16x8*)&hbuf[p][bB * HSTR + 32 + q8];
    int tok_cur = tokc[(t >> 4) & 1][bB * TSTR + (t & 15)];

    f32x4 acc0 = {0.f, 0.f, 0.f, 0.f};
    acc0 = __builtin_amdgcn_mfma_f32_16x16x32_bf16(Af[0][0], Bf0, acc0, 0, 0, 0);
    acc0 = __builtin_amdgcn_mfma_f32_16x16x32_bf16(Af[0][1], Bf1, acc0, 0, 0, 0);
    f32x4 acc1 = {0.f, 0.f, 0.f, 0.f};
    if (nt_own == 2) {
      acc1 = __builtin_amdgcn_mfma_f32_16x16x32_bf16(Af[1][0], Bf0, acc1, 0, 0, 0);
      acc1 = __builtin_amdgcn_mfma_f32_16x16x32_bf16(Af[1][1], Bf1, acc1, 0, 0, 0);
    }

    // utility wave: prefetch token chunk (load at step 0, store at step 15 of
    // each chunk) and write next step's one-hot rows into hbuf[pn]
    if (wv == 7) {
      int bb = lane >> 2, d4 = (lane & 3) * 4;
      if ((t & 15) == 0 && t + 16 < SEQ)
        tokreg = *(const int4*)&tokens[(b0 + bb) * SEQ + (t + 16) + d4];
      if ((t & 15) == 15 && t + 16 < SEQ)
        *(int4*)&tokc[((t >> 4) + 1) & 1][bb * TSTR + d4] = tokreg;
      int tn = t + 1, cb = (tn >> 4) & 1;
      for (int i = lane; i < 256; i += 64) {
        int b = i >> 4, v = i & 15;
        if (v < VOCAB) {
          int tk = tokc[cb][b * TSTR + (tn & 15)];
          hbuf[pn][b * HSTR + HID + v] = (tk == v) ? (short)0x3F80 : (short)0;
        }
      }
    }

    // epilogue: acc regs = (i,f,g,o) of hidden j for batch bB — lane-local
    const bool keep = (tok_cur != 0);   // PAD_IDX = 0 keeps old state
    {
      float gi = fsigm(acc0[0]), gf = fsigm(acc0[1]);
      float gg = ftanh(acc0[2]), go = fsigm(acc0[3]);
      float cn = gf * c0 + gi * gg;
      float hn = go * ftanh(cn);
      c0 = keep ? cn : c0;
      h0 = keep ? hn : h0;
      int j = t0 * 4 + jj;
      if (j < HID) hbuf[pn][bB * HSTR + j] = f2bf(h0);   // tile 12 pads j=50,51
    }
    if (nt_own == 2) {
      float gi = fsigm(acc1[0]), gf = fsigm(acc1[1]);
      float gg = ftanh(acc1[2]), go = fsigm(acc1[3]);
      float cn = gf * c1 + gi * gg;
      float hn = go * ftanh(cn);
      c1 = keep ? cn : c1;
      h1 = keep ? hn : h1;
      int j = (t0 + 1) * 4 + jj;                          // always < 48
      hbuf[pn][bB * HSTR + j] = f2bf(h1);
    }
  }

  // ---- final h (f32 from regs) -> MLP -> sigmoid
  {
    int j = t0 * 4 + jj;
    if (j < HID) hfin[bB * 52 + j] = h0;
    if (nt_own == 2) hfin[bB * 52 + (t0 + 1) * 4 + jj] = h1;
  }
  __syncthreads();
  for (int idx = tid; idx < 16 * 64; idx += 512) {
    int b = idx >> 6, m = idx & 63;
    if (m < HID) {
      float s = b1[m];
      for (int j2 = 0; j2 < HID; ++j2) s += hfin[b * 52 + j2] * W1[m * HID + j2];
      mlp_hid[b * 52 + m] = s;
    }
  }
  __syncthreads();
  if (tid < 16) {
    float s = b2[0];
    for (int m2 = 0; m2 < HID; ++m2) s += mlp_hid[tid * 52 + m2] * W2[m2];
    out[b0 + tid] = fsigm(s);
  }
}

extern "C" void kernel_launch(void* const* d_in, const int* in_sizes, int n_in,
                              void* d_out, int out_size, void* d_ws, size_t ws_size,
                              hipStream_t stream) {
  const int*   tokens = (const int*)  d_in[0];
  const float* emb    = (const float*)d_in[1];
  const float* W_ih   = (const float*)d_in[2];
  const float* W_hh   = (const float*)d_in[3];
  const float* b_ih   = (const float*)d_in[4];
  const float* b_hh   = (const float*)d_in[5];
  const float* W1     = (const float*)d_in[6];
  const float* b1     = (const float*)d_in[7];
  const float* W2     = (const float*)d_in[8];
  const float* b2     = (const float*)d_in[9];
  float* outp  = (float*)d_out;
  short* Apack = (short*)d_ws;                 // 13312 bf16 = 26.6 KB

  hipLaunchKernelGGL(prep_kernel, dim3(52), dim3(256), 0, stream,
                     emb, W_ih, W_hh, b_ih, b_hh, Apack);
  hipLaunchKernelGGL(lstm_kernel, dim3(BATCH / 16), dim3(512), 0, stream,
                     tokens, Apack, W1, b1, W2, b2, outp);
}

// Round 2
// 1134.693 us; speedup vs baseline: 1.2787x; 1.2787x over previous
//
#include <hip/hip_runtime.h>

#define BATCH 4096
#define SEQ   2048
#define EMB   10
#define HID   50
#define VOCAB 14
#define G4    200      // 4*HID gate rows
#define NT    13       // 13 N-tiles of 16 cover 208 >= 200 interleaved gate rows
#define HSTR  72       // bf16 stride of one batch row in h buffer (64 used + 8 pad)
#define TSTR  20       // int stride of token chunk row (16 used + 4 pad, keeps 16B align)

using bf16x8 = __attribute__((ext_vector_type(8))) short;
using f32x4  = __attribute__((ext_vector_type(4))) float;

__device__ __forceinline__ short f2bf(float f) {
  unsigned u = __builtin_bit_cast(unsigned, f);
  u = (u + 0x7FFFu + ((u >> 16) & 1u)) >> 16;   // round-to-nearest-even
  return (short)u;
}
__device__ __forceinline__ float fsigm(float x) {
  return __builtin_amdgcn_rcpf(1.0f + __builtin_amdgcn_exp2f(x * -1.44269504f));
}
__device__ __forceinline__ float ftanh(float x) {
  return 2.0f * __builtin_amdgcn_rcpf(1.0f + __builtin_amdgcn_exp2f(x * -2.88539008f)) - 1.0f;
}

// ---------------------------------------------------------------------------
// Setup: pack A-operand fragments (bf16) for mfma_f32_16x16x32_bf16.
// A[m][k] per tile t: m = lane&15 -> interleaved gate row n' = 16t+m
//                     k = kf*32 + (lane>>4)*8 + j
//   n' = 4*j_h + g  maps to original row r = 50*g + j_h  (i,f,g,o interleave)
//   k <  50 : W_hh[r][k]
//   k >= 50 : gxi[v = k-50][n'] = b_ih[r]+b_hh[r]+sum_e emb[v][e]*W_ih[r][e]
// (one-hot token rows fold embedding+input-proj+biases into the same MFMA)
// ---------------------------------------------------------------------------
__global__ void prep_kernel(const float* __restrict__ emb,  const float* __restrict__ W_ih,
                            const float* __restrict__ W_hh, const float* __restrict__ b_ih,
                            const float* __restrict__ b_hh, short* __restrict__ Apack) {
  int idx = blockIdx.x * 256 + threadIdx.x;       // total NT*2*64*8 = 13312
  if (idx >= NT * 2 * 64 * 8) return;
  int j    = idx & 7;
  int lane = (idx >> 3) & 63;
  int kf   = (idx >> 9) & 1;
  int t    = idx >> 10;
  int m    = lane & 15;
  int n    = t * 16 + m;                           // interleaved gate row
  int k    = kf * 32 + (lane >> 4) * 8 + j;
  float v = 0.0f;
  if (n < G4) {
    int jh = n >> 2, g = n & 3;
    int r  = g * HID + jh;                         // original gate row (i,f,g,o blocks)
    if (k < HID) {
      v = W_hh[r * HID + k];
    } else {
      int vo = k - HID;                            // vocab id 0..13
      float s = b_ih[r] + b_hh[r];
      for (int e = 0; e < EMB; ++e) s += emb[vo * EMB + e] * W_ih[r * EMB + e];
      v = s;
    }
  }
  Apack[idx] = f2bf(v);
}

// ---------------------------------------------------------------------------
// Main: 256 wgs x 1024 threads (16 waves), one wg owns 16 batch rows.
// Waves 0..12: one 16-gate-row tile each (perfectly balanced: 2 MFMA +
//   4-activation epilogue + one b16 h-write per lane per step).
// All 16 waves: one-hot token row for batch b=wv, next step (off critical
//   path — depends only on tokens, written right after the barrier).
// Wave 13: 16-step token chunk prefetch; LDS store at t%16==13 so the
//   cross-wave handoff crosses >=1 barrier before first use at t%16==15.
// ---------------------------------------------------------------------------
__global__ __launch_bounds__(1024, 1) void lstm_kernel(
    const int* __restrict__ tokens, const short* __restrict__ Apack,
    const float* __restrict__ W1, const float* __restrict__ b1,
    const float* __restrict__ W2, const float* __restrict__ b2,
    float* __restrict__ out) {
  __shared__ __align__(16) short hbuf[2][16 * HSTR];   // [buf][b][k] bf16: k<50 h, 50..63 onehot
  __shared__ __align__(16) int   tokc[2][16 * TSTR];   // token chunks (16 steps)
  __shared__ float hfin[16 * 52];                      // final h (f32)
  __shared__ float mlp_hid[16 * 52];

  const int tid  = threadIdx.x;
  const int lane = tid & 63;
  const int wv   = tid >> 6;
  const int b0   = blockIdx.x * 16;
  const int bB   = lane & 15;          // batch col (B-frag & C col)
  const int jj   = lane >> 4;          // quad -> hidden offset within tile
  const int q8   = jj * 8;             // k octet base
  const int jh   = wv * 4 + jj;        // hidden unit this lane produces (wv<13)
  const bool compute = (wv < NT);
  const bool hvalid  = compute && (jh < HID);   // tile 12 pads jh=50,51

  // persistent A fragment (weights + gxi), loaded once
  bf16x8 Af0 = {}, Af1 = {};
  if (compute) {
    Af0 = *(const bf16x8*)(Apack + ((wv * 2 + 0) * 64 + lane) * 8);
    Af1 = *(const bf16x8*)(Apack + ((wv * 2 + 1) * 64 + lane) * 8);
  }

  // ---- init: zero h rows of buf0, load token chunk 0
  for (int i = tid; i < 16 * HSTR; i += 1024) hbuf[0][i] = 0;
  int4 tokreg = {0, 0, 0, 0};
  const int bb = lane >> 2, d4 = (lane & 3) * 4;
  if (wv == 13) {
    tokreg = *(const int4*)&tokens[(b0 + bb) * SEQ + d4];
    *(int4*)&tokc[0][bb * TSTR + d4] = tokreg;
  }
  __syncthreads();
  // one-hot for t=0: wave w owns batch row w
  if (lane < VOCAB) {
    int tk = tokc[0][wv * TSTR];
    hbuf[0][wv * HSTR + HID + lane] = (tk == lane) ? (short)0x3F80 : (short)0;
  }

  float c0 = 0.f, h0 = 0.f;

  for (int t = 0; t < SEQ; ++t) {
    const int p = t & 1, pn = p ^ 1;
    __syncthreads();   // hbuf[p] (h + one-hot) and current token chunk ready

    // token chunk pipeline (wave 13): global load at chunk step 0, LDS store
    // at chunk step 13 (first cross-wave use is at step 15, behind 2 barriers)
    if (wv == 13) {
      if ((t & 15) == 0 && t + 16 < SEQ)
        tokreg = *(const int4*)&tokens[(b0 + bb) * SEQ + (t + 16) + d4];
      if ((t & 15) == 13 && t + 3 < SEQ)
        *(int4*)&tokc[((t >> 4) + 1) & 1][bb * TSTR + d4] = tokreg;
    }

    // next step's one-hot rows: wave w writes batch row w (independent of
    // this step's compute — issues immediately, off the critical path)
    {
      int tn = t + 1;
      if (tn < SEQ && lane < VOCAB) {
        int tk = tokc[(tn >> 4) & 1][wv * TSTR + (tn & 15)];
        hbuf[pn][wv * HSTR + HID + lane] = (tk == lane) ? (short)0x3F80 : (short)0;
      }
    }

    if (compute) {
      // B fragment: B[k][n=bB], k = q8..q8+7 (+32 for kf=1)
      bf16x8 Bf0 = *(const bf16x8*)&hbuf[p][bB * HSTR + q8];
      bf16x8 Bf1 = *(const bf16x8*)&hbuf[p][bB * HSTR + 32 + q8];
      int tok_cur = tokc[(t >> 4) & 1][bB * TSTR + (t & 15)];

      f32x4 acc = {0.f, 0.f, 0.f, 0.f};
      acc = __builtin_amdgcn_mfma_f32_16x16x32_bf16(Af0, Bf0, acc, 0, 0, 0);
      acc = __builtin_amdgcn_mfma_f32_16x16x32_bf16(Af1, Bf1, acc, 0, 0, 0);

      // acc regs = (i,f,g,o) of hidden jh for batch bB — lane-local
      float gi = fsigm(acc[0]), gf = fsigm(acc[1]);
      float gg = ftanh(acc[2]), go = fsigm(acc[3]);
      float cn = gf * c0 + gi * gg;
      float hn = go * ftanh(cn);
      const bool keep = (tok_cur != 0);   // PAD_IDX = 0 keeps old state
      c0 = keep ? cn : c0;
      h0 = keep ? hn : h0;
      if (hvalid) hbuf[pn][bB * HSTR + jh] = f2bf(h0);
    }
  }

  // ---- final h (f32 from regs) -> MLP -> sigmoid
  if (hvalid) hfin[bB * 52 + jh] = h0;
  __syncthreads();
  for (int idx = tid; idx < 16 * 64; idx += 1024) {
    int b = idx >> 6, m = idx & 63;
    if (m < HID) {
      float s = b1[m];
      for (int j2 = 0; j2 < HID; ++j2) s += hfin[b * 52 + j2] * W1[m * HID + j2];
      mlp_hid[b * 52 + m] = s;
    }
  }
  __syncthreads();
  if (tid < 16) {
    float s = b2[0];
    for (int m2 = 0; m2 < HID; ++m2) s += mlp_hid[tid * 52 + m2] * W2[m2];
    out[b0 + tid] = fsigm(s);
  }
}

extern "C" void kernel_launch(void* const* d_in, const int* in_sizes, int n_in,
                              void* d_out, int out_size, void* d_ws, size_t ws_size,
                              hipStream_t stream) {
  const int*   tokens = (const int*)  d_in[0];
  const float* emb    = (const float*)d_in[1];
  const float* W_ih   = (const float*)d_in[2];
  const float* W_hh   = (const float*)d_in[3];
  const float* b_ih   = (const float*)d_in[4];
  const float* b_hh   = (const float*)d_in[5];
  const float* W1     = (const float*)d_in[6];
  const float* b1     = (const float*)d_in[7];
  const float* W2     = (const float*)d_in[8];
  const float* b2     = (const float*)d_in[9];
  float* outp  = (float*)d_out;
  short* Apack = (short*)d_ws;                 // 13312 bf16 = 26.6 KB

  hipLaunchKernelGGL(prep_kernel, dim3(52), dim3(256), 0, stream,
                     emb, W_ih, W_hh, b_ih, b_hh, Apack);
  hipLaunchKernelGGL(lstm_kernel, dim3(BATCH / 16), dim3(1024), 0, stream,
                     tokens, Apack, W1, b1, W2, b2, outp);
}

// Round 3
// 1050.112 us; speedup vs baseline: 1.3817x; 1.0805x over previous
//
#include <hip/hip_runtime.h>

#define BATCH 4096
#define SEQ   2048
#define EMB   10
#define HID   50
#define VOCAB 14
#define G4    200      // 4*HID gate rows
#define NT    13       // 13 N-tiles of 16 cover 208 >= 200 interleaved gate rows
#define HSTR  72       // bf16 stride of one batch row in h buffer (64 used + 8 pad)
#define TSTR  20       // int stride of token chunk row (16 used + 4 pad, keeps 16B align)

using bf16x8 = __attribute__((ext_vector_type(8))) short;
using f32x4  = __attribute__((ext_vector_type(4))) float;

__device__ __forceinline__ short f2bf(float f) {
  unsigned u = __builtin_bit_cast(unsigned, f);
  u = (u + 0x7FFFu + ((u >> 16) & 1u)) >> 16;   // round-to-nearest-even
  return (short)u;
}
__device__ __forceinline__ float fsigm(float x) {
  return __builtin_amdgcn_rcpf(1.0f + __builtin_amdgcn_exp2f(x * -1.44269504f));
}

// ---------------------------------------------------------------------------
// Setup: pack A-operand fragments (bf16) for mfma_f32_16x16x32_bf16.
// Rows are PRE-SCALED: i/f/o gate rows by -log2(e), g rows by -2*log2(e), so
// the epilogue is sigma = rcp(1+exp2(acc)) and tanh = 2*rcp(1+exp2(acc))-1
// with no per-step multiply.
// A[m][k] per tile t: m = lane&15 -> interleaved gate row n' = 16t+m
//                     k = kf*32 + (lane>>4)*8 + j
//   n' = 4*j_h + g  maps to original row r = 50*g + j_h  (i,f,g,o interleave)
//   k <  50 : W_hh[r][k] * scale
//   k >= 50 : (b_ih[r]+b_hh[r]+sum_e emb[v][e]*W_ih[r][e]) * scale, v = k-50
// ---------------------------------------------------------------------------
__global__ void prep_kernel(const float* __restrict__ emb,  const float* __restrict__ W_ih,
                            const float* __restrict__ W_hh, const float* __restrict__ b_ih,
                            const float* __restrict__ b_hh, short* __restrict__ Apack) {
  int idx = blockIdx.x * 256 + threadIdx.x;       // total NT*2*64*8 = 13312
  if (idx >= NT * 2 * 64 * 8) return;
  int j    = idx & 7;
  int lane = (idx >> 3) & 63;
  int kf   = (idx >> 9) & 1;
  int t    = idx >> 10;
  int m    = lane & 15;
  int n    = t * 16 + m;                           // interleaved gate row
  int k    = kf * 32 + (lane >> 4) * 8 + j;
  float v = 0.0f;
  if (n < G4) {
    int jh = n >> 2, g = n & 3;
    int r  = g * HID + jh;                         // original gate row (i,f,g,o blocks)
    float scale = (g == 2) ? -2.885390082f : -1.442695041f;
    if (k < HID) {
      v = W_hh[r * HID + k] * scale;
    } else {
      int vo = k - HID;                            // vocab id 0..13
      float s = b_ih[r] + b_hh[r];
      for (int e = 0; e < EMB; ++e) s += emb[vo * EMB + e] * W_ih[r * EMB + e];
      v = s * scale;
    }
  }
  Apack[idx] = f2bf(v);
}

// ---------------------------------------------------------------------------
// Main: 256 wgs x 1024 threads (16 waves), one wg owns 16 batch rows.
// Waves 0..12: one 16-gate-row tile each. All waves: packed-b32 one-hot row
// for batch b=wv, next step. Wave 13: token chunk prefetch 2 chunks ahead
// (register double buffer) so HBM latency never lands on a barrier.
// Loop unrolled x2 -> ping-pong buffer indices are compile-time constants.
// ---------------------------------------------------------------------------
__global__ __launch_bounds__(1024, 1) void lstm_kernel(
    const int* __restrict__ tokens, const short* __restrict__ Apack,
    const float* __restrict__ W1, const float* __restrict__ b1,
    const float* __restrict__ W2, const float* __restrict__ b2,
    float* __restrict__ out) {
  __shared__ __align__(16) short hbuf[2][16 * HSTR];   // [buf][b][k] bf16: k<50 h, 50..63 onehot
  __shared__ __align__(16) int   tokc[2][16 * TSTR];   // token chunks (16 steps)
  __shared__ float hfin[16 * 52];                      // final h (f32)
  __shared__ float mlp_hid[16 * 52];

  const int tid  = threadIdx.x;
  const int lane = tid & 63;
  const int wv   = tid >> 6;
  const int b0   = blockIdx.x * 16;
  const int bB   = lane & 15;          // batch col (B-frag & C col)
  const int jj   = lane >> 4;          // quad -> hidden offset within tile
  const int q8   = jj * 8;             // k octet base
  const int jh   = wv * 4 + jj;        // hidden unit this lane produces (wv<13)
  const bool compute = (wv < NT);
  const bool hvalid  = compute && (jh < HID);   // tile 12 pads jh=50,51

  // persistent A fragment (pre-scaled weights + gxi), loaded once
  bf16x8 Af0 = {}, Af1 = {};
  if (compute) {
    Af0 = *(const bf16x8*)(Apack + ((wv * 2 + 0) * 64 + lane) * 8);
    Af1 = *(const bf16x8*)(Apack + ((wv * 2 + 1) * 64 + lane) * 8);
  }

  // ---- init: zero h rows of buf0, token chunk 0 -> LDS, chunk 1 -> regs
  for (int i = tid; i < 16 * HSTR; i += 1024) hbuf[0][i] = 0;
  int4 R0 = {0, 0, 0, 0}, R1 = {0, 0, 0, 0};
  const int bb = lane >> 2, d4 = (lane & 3) * 4;
  if (wv == 13) {
    int4 c0v = *(const int4*)&tokens[(b0 + bb) * SEQ + d4];
    *(int4*)&tokc[0][bb * TSTR + d4] = c0v;
    R0 = *(const int4*)&tokens[(b0 + bb) * SEQ + 16 + d4];   // chunk 1
  }
  __syncthreads();
  // one-hot for t=0 (packed b32, lanes 0..6), row wv
  if (lane < 7) {
    int tk = tokc[0][wv * TSTR];
    unsigned wbits = ((tk == 2 * lane) ? 0x3F80u : 0u) |
                     ((tk == 2 * lane + 1) ? 0x3F800000u : 0u);
    *(unsigned*)&hbuf[0][wv * HSTR + HID + 2 * lane] = wbits;
  }
  int tok_nxt = tokc[0][bB * TSTR];   // token for step 0

  float c0 = 0.f, h0 = 0.f;

#define STEP(T, PB, PN)                                                        \
  {                                                                            \
    __syncthreads();                                                           \
    bf16x8 Bf0, Bf1;                                                           \
    if (compute) {                                                             \
      Bf0 = *(const bf16x8*)&hbuf[PB][bB * HSTR + q8];                         \
      Bf1 = *(const bf16x8*)&hbuf[PB][bB * HSTR + 32 + q8];                    \
    }                                                                          \
    f32x4 acc = {0.f, 0.f, 0.f, 0.f};                                          \
    if (compute) {                                                             \
      acc = __builtin_amdgcn_mfma_f32_16x16x32_bf16(Af0, Bf0, acc, 0, 0, 0);   \
      acc = __builtin_amdgcn_mfma_f32_16x16x32_bf16(Af1, Bf1, acc, 0, 0, 0);   \
    }                                                                          \
    if (wv == 13) {                                                            \
      if (((T) & 15) == 0 && (T) + 32 < SEQ)                                   \
        R1 = *(const int4*)&tokens[(b0 + bb) * SEQ + (T) + 32 + d4];           \
      if (((T) & 15) == 13 && (T) + 3 < SEQ)                                   \
        *(int4*)&tokc[(((T) >> 4) + 1) & 1][bb * TSTR + d4] = R0;              \
      if (((T) & 15) == 15) R0 = R1;                                           \
    }                                                                          \
    { /* one-hot for step T+1 into hbuf[PN], batch row wv, lanes 0..6 */       \
      int tn = (T) + 1;                                                        \
      if (lane < 7) {                                                          \
        int tk = tokc[(tn >> 4) & 1][wv * TSTR + (tn & 15)];                   \
        unsigned wbits = ((tk == 2 * lane) ? 0x3F80u : 0u) |                   \
                         ((tk == 2 * lane + 1) ? 0x3F800000u : 0u);            \
        *(unsigned*)&hbuf[PN][wv * HSTR + HID + 2 * lane] = wbits;             \
      }                                                                        \
    }                                                                          \
    if (compute) {                                                             \
      int tok_use = tok_nxt;                                                   \
      tok_nxt = tokc[(((T) + 1) >> 4) & 1][bB * TSTR + (((T) + 1) & 15)];      \
      float gi = __builtin_amdgcn_rcpf(1.0f + __builtin_amdgcn_exp2f(acc[0])); \
      float gf = __builtin_amdgcn_rcpf(1.0f + __builtin_amdgcn_exp2f(acc[1])); \
      float gg = 2.0f * __builtin_amdgcn_rcpf(1.0f + __builtin_amdgcn_exp2f(acc[2])) - 1.0f; \
      float go = __builtin_amdgcn_rcpf(1.0f + __builtin_amdgcn_exp2f(acc[3])); \
      float cn = gf * c0 + gi * gg;                                            \
      float tn2 = 2.0f * __builtin_amdgcn_rcpf(1.0f + __builtin_amdgcn_exp2f(cn * -2.88539008f)) - 1.0f; \
      float hn = go * tn2;                                                     \
      const bool keep = (tok_use != 0);                                        \
      c0 = keep ? cn : c0;                                                     \
      h0 = keep ? hn : h0;                                                     \
      if (hvalid) hbuf[PN][bB * HSTR + jh] = f2bf(h0);                         \
    }                                                                          \
  }

  for (int t = 0; t < SEQ; t += 2) {
    STEP(t, 0, 1)
    STEP(t + 1, 1, 0)
  }
#undef STEP

  // ---- final h (f32 from regs) -> MLP -> sigmoid
  if (hvalid) hfin[bB * 52 + jh] = h0;
  __syncthreads();
  for (int idx = tid; idx < 16 * 64; idx += 1024) {
    int b = idx >> 6, m = idx & 63;
    if (m < HID) {
      float s = b1[m];
      for (int j2 = 0; j2 < HID; ++j2) s += hfin[b * 52 + j2] * W1[m * HID + j2];
      mlp_hid[b * 52 + m] = s;
    }
  }
  __syncthreads();
  if (tid < 16) {
    float s = b2[0];
    for (int m2 = 0; m2 < HID; ++m2) s += mlp_hid[tid * 52 + m2] * W2[m2];
    out[b0 + tid] = fsigm(s);
  }
}

extern "C" void kernel_launch(void* const* d_in, const int* in_sizes, int n_in,
                              void* d_out, int out_size, void* d_ws, size_t ws_size,
                              hipStream_t stream) {
  const int*   tokens = (const int*)  d_in[0];
  const float* emb    = (const float*)d_in[1];
  const float* W_ih   = (const float*)d_in[2];
  const float* W_hh   = (const float*)d_in[3];
  const float* b_ih   = (const float*)d_in[4];
  const float* b_hh   = (const float*)d_in[5];
  const float* W1     = (const float*)d_in[6];
  const float* b1     = (const float*)d_in[7];
  const float* W2     = (const float*)d_in[8];
  const float* b2     = (const float*)d_in[9];
  float* outp  = (float*)d_out;
  short* Apack = (short*)d_ws;                 // 13312 bf16 = 26.6 KB

  hipLaunchKernelGGL(prep_kernel, dim3(52), dim3(256), 0, stream,
                     emb, W_ih, W_hh, b_ih, b_hh, Apack);
  hipLaunchKernelGGL(lstm_kernel, dim3(BATCH / 16), dim3(1024), 0, stream,
                     tokens, Apack, W1, b1, W2, b2, outp);
}